// Round 4
// baseline (818.549 us; speedup 1.0000x reference)
//
#include <hip/hip_runtime.h>

typedef __bf16 bf16;
typedef __attribute__((ext_vector_type(4))) float f32x4;
typedef __attribute__((ext_vector_type(8))) __bf16 bf16x8;
typedef __attribute__((ext_vector_type(4))) __bf16 bf16x4;
typedef __attribute__((ext_vector_type(4))) int i32x4;

#define NN 8192
#define FI 512
#define FO 256
#define NSPLIT 4
#define JCHUNK (NN / NSPLIT)

// ---------------------------------------------------------------------------
// kw: W [512][256] f32 -> Wt_hi/Wt_lo [256][512] bf16 (transposed + split),
// so k1 can load B fragments straight from global (bf16x8 per lane).
// ---------------------------------------------------------------------------
__global__ __launch_bounds__(256) void kw_split(const float* __restrict__ W,
                                                bf16* __restrict__ wth,
                                                bf16* __restrict__ wtl) {
  const int idx = blockIdx.x * 256 + threadIdx.x;  // 512*256 = 131072
  const int k = idx >> 8, n = idx & 255;
  float x = W[idx];
  bf16 hi = (bf16)x;
  wth[(size_t)n * FI + k] = hi;
  wtl[(size_t)n * FI + k] = (bf16)(x - (float)hi);
}

// ---------------------------------------------------------------------------
// k1: Wh = h @ W + bW via split-bf16 MFMA (hi*hi + hi*lo + lo*hi, fp32 acc).
// Barrier-free; wave = 16 rows x 64 cols. Per k-step: issue all 8 B loads +
// next-h prefetch, then sched_barrier(0) pins them (R2/R3 lesson: without
// the pin the scheduler sinks loads next to each MFMA and serializes at
// full memory latency -- VGPR_Count 44 was the tell), then split VALU,
// then 12 MFMAs. Grid (256,2) = 512 blocks.
// ---------------------------------------------------------------------------
__global__ __launch_bounds__(256, 2) void k1_gemm(
    const float* __restrict__ h, const bf16* __restrict__ wth,
    const bf16* __restrict__ wtl, const float* __restrict__ bW,
    const float* __restrict__ a1, const float* __restrict__ a2,
    bf16* __restrict__ whb, float* __restrict__ f1, float* __restrict__ f2) {
  __shared__ bf16 stg[128 * 32];  // [n_local][il], 8 KB
  const int t = threadIdx.x;
  const int lane = t & 63, w = t >> 6;
  const int m16 = lane & 15, q = lane >> 4;
  const int wr = w & 1, wn = w >> 1;
  const int rb = blockIdx.x, bj = blockIdx.y;
  const int row = rb * 32 + wr * 16 + m16;  // A-fragment row for this lane
  const int nb = bj * 128 + wn * 64;

  const f32x4 z4 = {0.f, 0.f, 0.f, 0.f};
  f32x4 acc[4];
#pragma unroll
  for (int nn = 0; nn < 4; ++nn) acc[nn] = z4;

  const float* hrow = h + (size_t)row * FI + q * 8;
  const bf16* wthp = wth + (size_t)(nb + m16) * FI + q * 8;
  const bf16* wtlp = wtl + (size_t)(nb + m16) * FI + q * 8;

  const int KT = FI / 32;

#define K1_STEP(KIDX, hA0, hA1, hB0, hB1)                                     \
  {                                                                           \
    const int kt_ = (KIDX);                                                   \
    bf16x8 bh0 = *(const bf16x8*)(wthp + (size_t)0 * 16 * FI + kt_ * 32);     \
    bf16x8 bh1 = *(const bf16x8*)(wthp + (size_t)1 * 16 * FI + kt_ * 32);     \
    bf16x8 bh2 = *(const bf16x8*)(wthp + (size_t)2 * 16 * FI + kt_ * 32);     \
    bf16x8 bh3 = *(const bf16x8*)(wthp + (size_t)3 * 16 * FI + kt_ * 32);     \
    bf16x8 bl0 = *(const bf16x8*)(wtlp + (size_t)0 * 16 * FI + kt_ * 32);     \
    bf16x8 bl1 = *(const bf16x8*)(wtlp + (size_t)1 * 16 * FI + kt_ * 32);     \
    bf16x8 bl2 = *(const bf16x8*)(wtlp + (size_t)2 * 16 * FI + kt_ * 32);     \
    bf16x8 bl3 = *(const bf16x8*)(wtlp + (size_t)3 * 16 * FI + kt_ * 32);     \
    const int ktn_ = (kt_ + 1 < KT) ? kt_ + 1 : kt_;                          \
    hB0 = *(const f32x4*)(hrow + ktn_ * 32);                                  \
    hB1 = *(const f32x4*)(hrow + ktn_ * 32 + 4);                              \
    __builtin_amdgcn_sched_barrier(0);                                        \
    bf16x8 hh, hl;                                                            \
    _Pragma("unroll") for (int x = 0; x < 4; ++x) {                           \
      float v = hA0[x];                                                       \
      bf16 hi = (bf16)v;                                                      \
      hh[x] = hi;                                                             \
      hl[x] = (bf16)(v - (float)hi);                                          \
      float v2 = hA1[x];                                                      \
      bf16 hi2 = (bf16)v2;                                                    \
      hh[4 + x] = hi2;                                                        \
      hl[4 + x] = (bf16)(v2 - (float)hi2);                                    \
    }                                                                         \
    acc[0] = __builtin_amdgcn_mfma_f32_16x16x32_bf16(hh, bh0, acc[0], 0, 0, 0); \
    acc[0] = __builtin_amdgcn_mfma_f32_16x16x32_bf16(hl, bh0, acc[0], 0, 0, 0); \
    acc[0] = __builtin_amdgcn_mfma_f32_16x16x32_bf16(hh, bl0, acc[0], 0, 0, 0); \
    acc[1] = __builtin_amdgcn_mfma_f32_16x16x32_bf16(hh, bh1, acc[1], 0, 0, 0); \
    acc[1] = __builtin_amdgcn_mfma_f32_16x16x32_bf16(hl, bh1, acc[1], 0, 0, 0); \
    acc[1] = __builtin_amdgcn_mfma_f32_16x16x32_bf16(hh, bl1, acc[1], 0, 0, 0); \
    acc[2] = __builtin_amdgcn_mfma_f32_16x16x32_bf16(hh, bh2, acc[2], 0, 0, 0); \
    acc[2] = __builtin_amdgcn_mfma_f32_16x16x32_bf16(hl, bh2, acc[2], 0, 0, 0); \
    acc[2] = __builtin_amdgcn_mfma_f32_16x16x32_bf16(hh, bl2, acc[2], 0, 0, 0); \
    acc[3] = __builtin_amdgcn_mfma_f32_16x16x32_bf16(hh, bh3, acc[3], 0, 0, 0); \
    acc[3] = __builtin_amdgcn_mfma_f32_16x16x32_bf16(hl, bh3, acc[3], 0, 0, 0); \
    acc[3] = __builtin_amdgcn_mfma_f32_16x16x32_bf16(hh, bl3, acc[3], 0, 0, 0); \
  }

  f32x4 hA0 = *(const f32x4*)(hrow);
  f32x4 hA1 = *(const f32x4*)(hrow + 4);
  f32x4 hB0, hB1;
  for (int kt = 0; kt < KT; kt += 2) {
    K1_STEP(kt, hA0, hA1, hB0, hB1);
    K1_STEP(kt + 1, hB0, hB1, hA0, hA1);
  }
#undef K1_STEP

  // Epilogue. C/D layout: col = lane&15 (n), row = q*4+reg (i within 16-tile).
  float f1p[4] = {}, f2p[4] = {};
  const int il = wr * 16 + q * 4;
#pragma unroll
  for (int nn = 0; nn < 4; ++nn) {
    const int n = nb + nn * 16 + m16;
    const int nl = wn * 64 + nn * 16 + m16;  // local n within block (0..127)
    const float bw = bW[n], av1 = a1[n], av2 = a2[n];
    bf16x4 st;
#pragma unroll
    for (int reg = 0; reg < 4; ++reg) {
      float wh = acc[nn][reg] + bw;
      st[reg] = (bf16)wh;
      f1p[reg] += wh * av1;
      f2p[reg] += wh * av2;
    }
    *(bf16x4*)&stg[nl * 32 + il] = st;
  }
#pragma unroll
  for (int m = 1; m < 16; m <<= 1) {
#pragma unroll
    for (int reg = 0; reg < 4; ++reg) {
      f1p[reg] += __shfl_xor(f1p[reg], m);
      f2p[reg] += __shfl_xor(f2p[reg], m);
    }
  }
  if (m16 == 0) {
#pragma unroll
    for (int reg = 0; reg < 4; ++reg) {
      const int i = rb * 32 + wr * 16 + q * 4 + reg;
      atomicAdd(&f1[i], f1p[reg]);
      atomicAdd(&f2[i], f2p[reg]);
    }
  }
  __syncthreads();
  // Coalesced whb store: block region is 4096 contiguous bf16 (8 KB).
  bf16x8* dst = (bf16x8*)(whb + (size_t)rb * (FO * 32) + (size_t)bj * (128 * 32));
  const bf16x8* srcv = (const bf16x8*)stg;
#pragma unroll
  for (int u = 0; u < 2; ++u) dst[t * 2 + u] = srcv[t * 2 + u];
}

// ---------------------------------------------------------------------------
// k4: fused masked-softmax GEMM partial (j-split x NSPLIT), adj read fused.
// Barrier-free; P never touches LDS (lane (m16,q) holds A-frag row=m16,
// j=q*8..+7 directly). Per k-step: (1) all 8 B-fragment loads issued
// back-to-back, (2) adj/f2 prefetch for the NEXT k-step, (3)
// sched_barrier(0) -- pins the loads above the compute so the scheduler
// cannot sink them to the MFMAs (R3's VGPR_Count=44 proved it does exactly
// that without the pin, serializing at ~9000 cyc/step), (4) scores from the
// PREVIOUS step's adj/f2 (counted waitcnt only -- those loads are a full
// iteration old), (5) 8 MFMAs (waitcnt on this step's B loads, hidden under
// the score VALU + 4 waves/SIMD). adj/f2 ring: unroll-by-2 with NAMED slots
// (no runtime-indexed rotation -> no copies/scratch).
// Softmax shift: sh = lrelu(ci + 8) >= row max (|f2| << 8); cancels in acc/l.
// Grid (256, NSPLIT) = 1024 blocks -> 4/CU, 4 waves/SIMD.
// ---------------------------------------------------------------------------
__global__ __launch_bounds__(256, 4) void k4_attn(
    const int* __restrict__ adj, const bf16* __restrict__ whb,
    const float* __restrict__ f1, const float* __restrict__ f2,
    const float* __restrict__ ba_p,
    float* __restrict__ acc_part, float* __restrict__ l_part) {
  const int t = threadIdx.x;
  const int lane = t & 63, w = t >> 6;
  const int m16 = lane & 15, q = lane >> 4;
  const int wr = w & 1, wn = w >> 1;
  const int rb = blockIdx.x, s = blockIdx.y;
  const int i0 = rb * 32;
  const int row = i0 + wr * 16 + m16;  // score/A-fragment row for this lane

  const float ba = *ba_p;
  const float ci = f1[row] + ba;
  const float arg0 = ci + 8.0f;
  const float sh = fmaxf(arg0, 0.2f * arg0);

  const f32x4 z4 = {0.f, 0.f, 0.f, 0.f};
  f32x4 acc[8];
#pragma unroll
  for (int nn = 0; nn < 8; ++nn) acc[nn] = z4;
  float lreg = 0.f;

  const int sbase = s * JCHUNK;
  const int* arow = adj + (size_t)row * NN + sbase + q * 8;
  const float* frow = f2 + sbase + q * 8;
  const bf16* bptr = whb + (size_t)(sbase >> 5) * (FO * 32) +
                     (size_t)(wn * 128 + m16) * 32 + q * 8;

  const int KT = JCHUNK / 32;

#define K4_STEP(KIDX, cA0, cA1, gA0, gA1, cB0, cB1, gB0, gB1)                 \
  {                                                                           \
    const int kt_ = (KIDX);                                                   \
    const bf16* bk = bptr + (size_t)kt_ * (FO * 32);                          \
    bf16x8 cb0 = *(const bf16x8*)(bk + 0 * 512);                              \
    bf16x8 cb1 = *(const bf16x8*)(bk + 1 * 512);                              \
    bf16x8 cb2 = *(const bf16x8*)(bk + 2 * 512);                              \
    bf16x8 cb3 = *(const bf16x8*)(bk + 3 * 512);                              \
    bf16x8 cb4 = *(const bf16x8*)(bk + 4 * 512);                              \
    bf16x8 cb5 = *(const bf16x8*)(bk + 5 * 512);                              \
    bf16x8 cb6 = *(const bf16x8*)(bk + 6 * 512);                              \
    bf16x8 cb7 = *(const bf16x8*)(bk + 7 * 512);                              \
    const int ktn_ = (kt_ + 1 < KT) ? kt_ + 1 : kt_;                          \
    cB0 = *(const i32x4*)(arow + ktn_ * 32);                                  \
    cB1 = *(const i32x4*)(arow + ktn_ * 32 + 4);                              \
    gB0 = *(const f32x4*)(frow + ktn_ * 32);                                  \
    gB1 = *(const f32x4*)(frow + ktn_ * 32 + 4);                              \
    __builtin_amdgcn_sched_barrier(0);                                        \
    float pv[8];                                                              \
    _Pragma("unroll") for (int x = 0; x < 4; ++x) {                           \
      float arg = ci + gA0[x];                                                \
      float e = fmaxf(arg, 0.2f * arg);                                       \
      pv[x] = (cA0[x] > 0) ? __expf(e - sh) : 0.f;                            \
      float arg2 = ci + gA1[x];                                               \
      float e2 = fmaxf(arg2, 0.2f * arg2);                                    \
      pv[4 + x] = (cA1[x] > 0) ? __expf(e2 - sh) : 0.f;                       \
    }                                                                         \
    bf16x8 af;                                                                \
    _Pragma("unroll") for (int x = 0; x < 8; ++x) {                           \
      lreg += pv[x];                                                          \
      af[x] = (bf16)pv[x];                                                    \
    }                                                                         \
    acc[0] = __builtin_amdgcn_mfma_f32_16x16x32_bf16(af, cb0, acc[0], 0, 0, 0); \
    acc[1] = __builtin_amdgcn_mfma_f32_16x16x32_bf16(af, cb1, acc[1], 0, 0, 0); \
    acc[2] = __builtin_amdgcn_mfma_f32_16x16x32_bf16(af, cb2, acc[2], 0, 0, 0); \
    acc[3] = __builtin_amdgcn_mfma_f32_16x16x32_bf16(af, cb3, acc[3], 0, 0, 0); \
    acc[4] = __builtin_amdgcn_mfma_f32_16x16x32_bf16(af, cb4, acc[4], 0, 0, 0); \
    acc[5] = __builtin_amdgcn_mfma_f32_16x16x32_bf16(af, cb5, acc[5], 0, 0, 0); \
    acc[6] = __builtin_amdgcn_mfma_f32_16x16x32_bf16(af, cb6, acc[6], 0, 0, 0); \
    acc[7] = __builtin_amdgcn_mfma_f32_16x16x32_bf16(af, cb7, acc[7], 0, 0, 0); \
  }

  i32x4 sa0 = *(const i32x4*)(arow);
  i32x4 sa1 = *(const i32x4*)(arow + 4);
  f32x4 sf0 = *(const f32x4*)(frow);
  f32x4 sf1 = *(const f32x4*)(frow + 4);
  i32x4 sb0, sb1;
  f32x4 sg0, sg1;
  for (int kt = 0; kt < KT; kt += 2) {
    K4_STEP(kt, sa0, sa1, sf0, sf1, sb0, sb1, sg0, sg1);
    K4_STEP(kt + 1, sb0, sb1, sg0, sg1, sa0, sa1, sf0, sf1);
  }
#undef K4_STEP

  // l row-sum: 4 q-lanes share a row; n-half waves hold identical lreg.
  lreg += __shfl_xor(lreg, 16);
  lreg += __shfl_xor(lreg, 32);
  if (q == 0 && wn == 0) l_part[(size_t)s * NN + row] = lreg;
  // C/D: col = lane&15 (n), row = q*4+reg
  float* ap = acc_part + (size_t)s * ((size_t)NN * FO);
  const int r0 = i0 + wr * 16 + q * 4;
#pragma unroll
  for (int nn = 0; nn < 8; ++nn) {
    const int n = wn * 128 + nn * 16 + m16;
#pragma unroll
    for (int reg = 0; reg < 4; ++reg) {
      ap[(size_t)(r0 + reg) * FO + n] = acc[nn][reg];
    }
  }
}

// ---------------------------------------------------------------------------
// k5: out[i][n] = (sum_s acc_part[s][i][n]) / (sum_s l_part[s][i])
// ---------------------------------------------------------------------------
__global__ __launch_bounds__(256) void k5_reduce(
    const float* __restrict__ accp, const float* __restrict__ lp,
    float* __restrict__ out) {
  const int idx = blockIdx.x * 256 + threadIdx.x;
  const int i = idx >> 6, n4 = (idx & 63) * 4;
  f32x4 sum = {0.f, 0.f, 0.f, 0.f};
  float l = 0.f;
#pragma unroll
  for (int s = 0; s < NSPLIT; ++s) {
    sum += *(const f32x4*)&accp[(size_t)s * ((size_t)NN * FO) + (size_t)i * FO + n4];
    l += lp[s * NN + i];
  }
  const float rl = 1.0f / l;
  f32x4 o = sum * rl;
  *(f32x4*)&out[(size_t)i * FO + n4] = o;
}

// ---------------------------------------------------------------------------
// Workspace layout:
//   [0, 4MB)        whb  (bf16 Wh, fragment-major)
//   4MB             f1   (32 KB)
//   +32KB           f2   (32 KB)
//   4MB+64KB        acc_part[4][8192][256] f32 (32 MB)
//   +...            l_part[4][8192] f32 (128 KB)
//   +...            wth (256 KB), wtl (256 KB)
// total ~36.9 MB
// ---------------------------------------------------------------------------
extern "C" void kernel_launch(void* const* d_in, const int* in_sizes, int n_in,
                              void* d_out, int out_size, void* d_ws, size_t ws_size,
                              hipStream_t stream) {
  const float* h   = (const float*)d_in[0];
  const int*   adj = (const int*)d_in[1];
  const float* W   = (const float*)d_in[2];
  const float* bW  = (const float*)d_in[3];
  const float* a1  = (const float*)d_in[4];
  const float* a2  = (const float*)d_in[5];
  const float* ba  = (const float*)d_in[6];
  float* out = (float*)d_out;

  char* ws = (char*)d_ws;
  bf16* whb   = (bf16*)ws;
  float* f1   = (float*)(ws + 4u * 1024 * 1024);
  float* f2   = (float*)(ws + 4u * 1024 * 1024 + 32 * 1024);
  float* accp = (float*)(ws + 4u * 1024 * 1024 + 64 * 1024);
  float* lp   = accp + (size_t)NSPLIT * NN * FO;
  bf16* wth   = (bf16*)((char*)lp + (size_t)NSPLIT * NN * 4);
  bf16* wtl   = wth + (size_t)FO * FI;

  hipMemsetAsync(f1, 0, 64 * 1024, stream);  // zero f1+f2 (atomic targets)

  kw_split<<<FI * FO / 256, 256, 0, stream>>>(W, wth, wtl);
  k1_gemm<<<dim3(NN / 32, 2), 256, 0, stream>>>(h, wth, wtl, bW, a1, a2, whb, f1, f2);
  k4_attn<<<dim3(NN / 32, NSPLIT), 256, 0, stream>>>(adj, whb, f1, f2, ba, accp, lp);
  k5_reduce<<<(NN * FO / 4) / 256, 256, 0, stream>>>(accp, lp, out);
}

// Round 6
// 775.627 us; speedup vs baseline: 1.0553x; 1.0553x over previous
//
#include <hip/hip_runtime.h>

typedef __bf16 bf16;
typedef __attribute__((ext_vector_type(4))) float f32x4;
typedef __attribute__((ext_vector_type(8))) __bf16 bf16x8;
typedef __attribute__((ext_vector_type(4))) __bf16 bf16x4;
typedef __attribute__((ext_vector_type(4))) int i32x4;

#define NN 8192
#define FI 512
#define FO 256

#define MFMA16 __builtin_amdgcn_mfma_f32_16x16x32_bf16

// ---------------------------------------------------------------------------
// kw: W [512][256] f32 -> Wt_hi/Wt_lo [256][512] bf16 (transposed + split),
// so k1 can load B fragments straight from global (bf16x8 per lane).
// ---------------------------------------------------------------------------
__global__ __launch_bounds__(256) void kw_split(const float* __restrict__ W,
                                                bf16* __restrict__ wth,
                                                bf16* __restrict__ wtl) {
  const int idx = blockIdx.x * 256 + threadIdx.x;  // 512*256 = 131072
  const int k = idx >> 8, n = idx & 255;
  float x = W[idx];
  bf16 hi = (bf16)x;
  wth[(size_t)n * FI + k] = hi;
  wtl[(size_t)n * FI + k] = (bf16)(x - (float)hi);
}

// ---------------------------------------------------------------------------
// k1: Wh = h @ W + bW via split-bf16 MFMA (hi*hi + hi*lo + lo*hi, fp32 acc).
// Barrier-free main loop; wave = 16 rows x 64 cols (acc[4]). Short K (16
// steps) so even partially-serialized B loads cost little. Epilogue stages
// whb through LDS -> one coalesced 8 KB linear store per block; f1/f2 via
// shfl-reduce + atomicAdd. Grid (256,2) = 512 blocks.
// ---------------------------------------------------------------------------
__global__ __launch_bounds__(256, 2) void k1_gemm(
    const float* __restrict__ h, const bf16* __restrict__ wth,
    const bf16* __restrict__ wtl, const float* __restrict__ bW,
    const float* __restrict__ a1, const float* __restrict__ a2,
    bf16* __restrict__ whb, float* __restrict__ f1, float* __restrict__ f2) {
  __shared__ bf16 stg[128 * 32];  // [n_local][il], 8 KB
  const int t = threadIdx.x;
  const int lane = t & 63, w = t >> 6;
  const int m16 = lane & 15, q = lane >> 4;
  const int wr = w & 1, wn = w >> 1;
  const int rb = blockIdx.x, bj = blockIdx.y;
  const int row = rb * 32 + wr * 16 + m16;  // A-fragment row for this lane
  const int nb = bj * 128 + wn * 64;

  const f32x4 z4 = {0.f, 0.f, 0.f, 0.f};
  f32x4 acc[4];
#pragma unroll
  for (int nn = 0; nn < 4; ++nn) acc[nn] = z4;

  const float* hrow = h + (size_t)row * FI + q * 8;
  const bf16* wthp = wth + (size_t)(nb + m16) * FI + q * 8;
  const bf16* wtlp = wtl + (size_t)(nb + m16) * FI + q * 8;

  f32x4 nh0 = *(const f32x4*)(hrow);
  f32x4 nh1 = *(const f32x4*)(hrow + 4);

  const int KT = FI / 32;
  for (int kt = 0; kt < KT; ++kt) {
    bf16x8 bh[4], bl[4];
#pragma unroll
    for (int nn = 0; nn < 4; ++nn) {
      const size_t woff = (size_t)(nn * 16) * FI + kt * 32;
      bh[nn] = *(const bf16x8*)(wthp + woff);
      bl[nn] = *(const bf16x8*)(wtlp + woff);
    }
    const f32x4 h0 = nh0, h1 = nh1;
    const int ktn = (kt + 1 < KT) ? kt + 1 : kt;
    nh0 = *(const f32x4*)(hrow + ktn * 32);
    nh1 = *(const f32x4*)(hrow + ktn * 32 + 4);
    bf16x8 hh, hl;
#pragma unroll
    for (int x = 0; x < 4; ++x) {
      float v = h0[x];
      bf16 hi = (bf16)v;
      hh[x] = hi;
      hl[x] = (bf16)(v - (float)hi);
      float v2 = h1[x];
      bf16 hi2 = (bf16)v2;
      hh[4 + x] = hi2;
      hl[4 + x] = (bf16)(v2 - (float)hi2);
    }
#pragma unroll
    for (int nn = 0; nn < 4; ++nn) {
      acc[nn] = MFMA16(hh, bh[nn], acc[nn], 0, 0, 0);
      acc[nn] = MFMA16(hl, bh[nn], acc[nn], 0, 0, 0);
      acc[nn] = MFMA16(hh, bl[nn], acc[nn], 0, 0, 0);
    }
  }
  // Epilogue. C/D layout: col = lane&15 (n), row = q*4+reg (i within 16-tile).
  float f1p[4] = {}, f2p[4] = {};
  const int il = wr * 16 + q * 4;
#pragma unroll
  for (int nn = 0; nn < 4; ++nn) {
    const int n = nb + nn * 16 + m16;
    const int nl = wn * 64 + nn * 16 + m16;  // local n within block (0..127)
    const float bw = bW[n], av1 = a1[n], av2 = a2[n];
    bf16x4 st;
#pragma unroll
    for (int reg = 0; reg < 4; ++reg) {
      float wh = acc[nn][reg] + bw;
      st[reg] = (bf16)wh;
      f1p[reg] += wh * av1;
      f2p[reg] += wh * av2;
    }
    *(bf16x4*)&stg[nl * 32 + il] = st;
  }
#pragma unroll
  for (int m = 1; m < 16; m <<= 1) {
#pragma unroll
    for (int reg = 0; reg < 4; ++reg) {
      f1p[reg] += __shfl_xor(f1p[reg], m);
      f2p[reg] += __shfl_xor(f2p[reg], m);
    }
  }
  if (m16 == 0) {
#pragma unroll
    for (int reg = 0; reg < 4; ++reg) {
      const int i = rb * 32 + wr * 16 + q * 4 + reg;
      atomicAdd(&f1[i], f1p[reg]);
      atomicAdd(&f2[i], f2p[reg]);
    }
  }
  __syncthreads();
  // Coalesced whb store: block region is 4096 contiguous bf16 (8 KB).
  bf16x8* dst = (bf16x8*)(whb + (size_t)rb * (FO * 32) + (size_t)bj * (128 * 32));
  const bf16x8* srcv = (const bf16x8*)stg;
#pragma unroll
  for (int u = 0; u < 2; ++u) dst[t * 2 + u] = srcv[t * 2 + u];
}

// ---------------------------------------------------------------------------
// k4a: masked exp-scores, pure streaming (k0-shaped: no LDS, no barriers,
// no MFMA -- nothing for the scheduler to break). Wave = 16 rows x 512 j.
// Lane (m16,q) scores row m16, j = q*8..+7 per 32-j tile, i.e. EXACTLY one
// MFMA A-fragment lane -> P tile written as 64 lanes x bf16x8 = 1 KB
// coalesced. adj read: 16 x 128 B contiguous row segments per load pair
// (full cache-line utilization). Row sums -> one atomicAdd per row per wave
// (l prezeroed). Softmax shift: sh = lrelu(ci + 8) >= row max (|f2| << 8);
// cancels exactly in num/denom.
// Work: (8192/16 row tiles) x (8192/512 j-splits) = 8192 waves = 2048 blocks
// (R5 bug: launched 512 blocks -> 3/4 of P unwritten -> absmax inf).
// Traffic: adj 268 MB R + P 134 MB W => ~75 us at stream rate.
// ---------------------------------------------------------------------------
__global__ __launch_bounds__(256) void k4a_scores(
    const int* __restrict__ adj, const float* __restrict__ f1,
    const float* __restrict__ f2, const float* __restrict__ ba_p,
    bf16* __restrict__ P, float* __restrict__ l) {
  const int t = threadIdx.x;
  const int lane = t & 63, w = t >> 6;
  const int m16 = lane & 15, q = lane >> 4;
  const int gw = blockIdx.x * 4 + w;  // 0..8191
  const int ib = gw >> 4;             // row-tile (16 rows), 0..511
  const int js = gw & 15;             // j-split (512 j), 0..15
  const int row = ib * 16 + m16;
  const int j0 = js * 512;

  const float ba = *ba_p;
  const float ci = f1[row] + ba;
  const float arg0 = ci + 8.0f;
  const float sh = fmaxf(arg0, 0.2f * arg0);

  const int* arow = adj + (size_t)row * NN + j0 + q * 8;
  const float* frow = f2 + j0 + q * 8;
  // P tile a = ib*256 + js*16 + jt; lane slot = tile*512 + lane*8
  bf16* ptile = P + (size_t)(ib * 256 + js * 16) * 512 + lane * 8;

  float lreg = 0.f;
#pragma unroll 4
  for (int jt = 0; jt < 16; ++jt) {
    i32x4 a0 = *(const i32x4*)(arow + jt * 32);
    i32x4 a1 = *(const i32x4*)(arow + jt * 32 + 4);
    f32x4 g0 = *(const f32x4*)(frow + jt * 32);
    f32x4 g1 = *(const f32x4*)(frow + jt * 32 + 4);
    float pv[8];
#pragma unroll
    for (int x = 0; x < 4; ++x) {
      float arg = ci + g0[x];
      float e = fmaxf(arg, 0.2f * arg);
      pv[x] = (a0[x] > 0) ? __expf(e - sh) : 0.f;
      float arg2 = ci + g1[x];
      float e2 = fmaxf(arg2, 0.2f * arg2);
      pv[4 + x] = (a1[x] > 0) ? __expf(e2 - sh) : 0.f;
    }
    bf16x8 pb;
#pragma unroll
    for (int x = 0; x < 8; ++x) {
      lreg += pv[x];
      pb[x] = (bf16)pv[x];
    }
    *(bf16x8*)(ptile + (size_t)jt * 512) = pb;
  }
  // sum over the 4 q-lanes sharing a row, then one atomic per row
  lreg += __shfl_xor(lreg, 16);
  lreg += __shfl_xor(lreg, 32);
  if (q == 0) atomicAdd(&l[row], lreg);
}

// ---------------------------------------------------------------------------
// k4b: out = (P @ Wh) / l.  M=8192, N=256, K=8192. BOTH operands are
// fragment-major, so A and B are single bf16x8 per-lane loads -- no LDS, no
// barriers, no layout shuffles. 256 blocks x 512 threads (8 waves): wave =
// 16 rows x 64 n (4 B-frags, acc[4]); wr pairs split rows, wn splits n into
// quarters (A loads duplicated across wn -> L1 hits; whb is L2-resident).
// Loop-carried named double-buffer for A+B; __launch_bounds__(512,2) gives
// a 256-VGPR budget (~70 needed) so the allocator never recycles one slot
// through the loads (the R2-R4 serialization/spill trap). P was written by
// k4a just before -> mostly L3-resident (134 MB < 256 MB L3).
// ---------------------------------------------------------------------------
__global__ __launch_bounds__(512, 2) void k4b_gemm(
    const bf16* __restrict__ P, const bf16* __restrict__ whb,
    const float* __restrict__ l, float* __restrict__ out) {
  const int t = threadIdx.x;
  const int lane = t & 63, w = t >> 6;  // 8 waves
  const int m16 = lane & 15, q = lane >> 4;
  const int wr = w & 1, wn = w >> 1;    // wr: row half, wn: n quarter
  const int rb = blockIdx.x;            // 32 rows per block
  const int i0 = rb * 32;
  const int itile = rb * 2 + wr;        // 16-row A-tile index

  const bf16* aptr = P + (size_t)itile * 256 * 512 + lane * 8;
  const bf16* bptr = whb + (size_t)(wn * 64 + m16) * 32 + q * 8;
  const size_t BSTRIDE = (size_t)FO * 32;  // elems per 32-j block

  const f32x4 z4 = {0.f, 0.f, 0.f, 0.f};
  f32x4 acc0 = z4, acc1 = z4, acc2 = z4, acc3 = z4;

  bf16x8 aA = *(const bf16x8*)(aptr);
  bf16x8 bA0 = *(const bf16x8*)(bptr);
  bf16x8 bA1 = *(const bf16x8*)(bptr + 512);
  bf16x8 bA2 = *(const bf16x8*)(bptr + 1024);
  bf16x8 bA3 = *(const bf16x8*)(bptr + 1536);
  bf16x8 aB, bB0, bB1, bB2, bB3;

  const int KB = NN / 32;  // 256
  for (int jb = 0; jb < KB; jb += 2) {
    {  // even step: consume (aA,bA*), prefetch jb+1 into (aB,bB*)
      const int jn = jb + 1;
      aB = *(const bf16x8*)(aptr + (size_t)jn * 512);
      const bf16* bk = bptr + (size_t)jn * BSTRIDE;
      bB0 = *(const bf16x8*)(bk);
      bB1 = *(const bf16x8*)(bk + 512);
      bB2 = *(const bf16x8*)(bk + 1024);
      bB3 = *(const bf16x8*)(bk + 1536);
      acc0 = MFMA16(aA, bA0, acc0, 0, 0, 0);
      acc1 = MFMA16(aA, bA1, acc1, 0, 0, 0);
      acc2 = MFMA16(aA, bA2, acc2, 0, 0, 0);
      acc3 = MFMA16(aA, bA3, acc3, 0, 0, 0);
    }
    {  // odd step: consume (aB,bB*), prefetch jb+2 into (aA,bA*)
      const int jn = (jb + 2 < KB) ? jb + 2 : 0;  // clamped (harmless reload)
      aA = *(const bf16x8*)(aptr + (size_t)jn * 512);
      const bf16* bk = bptr + (size_t)jn * BSTRIDE;
      bA0 = *(const bf16x8*)(bk);
      bA1 = *(const bf16x8*)(bk + 512);
      bA2 = *(const bf16x8*)(bk + 1024);
      bA3 = *(const bf16x8*)(bk + 1536);
      acc0 = MFMA16(aB, bB0, acc0, 0, 0, 0);
      acc1 = MFMA16(aB, bB1, acc1, 0, 0, 0);
      acc2 = MFMA16(aB, bB2, acc2, 0, 0, 0);
      acc3 = MFMA16(aB, bB3, acc3, 0, 0, 0);
    }
  }
  // Epilogue: divide by l and store. C/D: col = lane&15 (n), row = q*4+reg.
  const int r0 = i0 + wr * 16 + q * 4;
  float rl[4];
#pragma unroll
  for (int reg = 0; reg < 4; ++reg) rl[reg] = 1.0f / l[r0 + reg];
  f32x4 accs[4] = {acc0, acc1, acc2, acc3};
#pragma unroll
  for (int nn = 0; nn < 4; ++nn) {
    const int n = wn * 64 + nn * 16 + m16;
#pragma unroll
    for (int reg = 0; reg < 4; ++reg) {
      out[(size_t)(r0 + reg) * FO + n] = accs[nn][reg] * rl[reg];
    }
  }
}

// ---------------------------------------------------------------------------
// Workspace layout:
//   [0, 4MB)          whb  (bf16 Wh, fragment-major)
//   4MB               f1   (32 KB)
//   +32KB             f2   (32 KB)
//   +64KB             l    (32 KB)   <- f1/f2/l contiguous, one 96 KB memset
//   4MB+96KB          wth (256 KB), wtl (256 KB)
//   8MB               P    (bf16 scores, A-fragment-major, 134.2 MB)
// total ~143 MB
// ---------------------------------------------------------------------------
extern "C" void kernel_launch(void* const* d_in, const int* in_sizes, int n_in,
                              void* d_out, int out_size, void* d_ws, size_t ws_size,
                              hipStream_t stream) {
  const float* h   = (const float*)d_in[0];
  const int*   adj = (const int*)d_in[1];
  const float* W   = (const float*)d_in[2];
  const float* bW  = (const float*)d_in[3];
  const float* a1  = (const float*)d_in[4];
  const float* a2  = (const float*)d_in[5];
  const float* ba  = (const float*)d_in[6];
  float* out = (float*)d_out;

  char* ws = (char*)d_ws;
  bf16* whb = (bf16*)ws;
  float* f1 = (float*)(ws + 4u * 1024 * 1024);
  float* f2 = (float*)(ws + 4u * 1024 * 1024 + 32 * 1024);
  float* l  = (float*)(ws + 4u * 1024 * 1024 + 64 * 1024);
  bf16* wth = (bf16*)(ws + 4u * 1024 * 1024 + 96 * 1024);
  bf16* wtl = wth + (size_t)FO * FI;
  bf16* P   = (bf16*)(ws + 8u * 1024 * 1024);

  hipMemsetAsync(f1, 0, 96 * 1024, stream);  // zero f1+f2+l (atomic targets)

  kw_split<<<FI * FO / 256, 256, 0, stream>>>(W, wth, wtl);
  k1_gemm<<<dim3(NN / 32, 2), 256, 0, stream>>>(h, wth, wtl, bW, a1, a2, whb, f1, f2);
  k4a_scores<<<NN / 4, 256, 0, stream>>>(adj, f1, f2, ba, P, l);  // 2048 blocks
  k4b_gemm<<<NN / 32, 512, 0, stream>>>(P, whb, l, out);
}

// Round 7
// 621.049 us; speedup vs baseline: 1.3180x; 1.2489x over previous
//
#include <hip/hip_runtime.h>

typedef __bf16 bf16;
typedef __attribute__((ext_vector_type(4))) float f32x4;
typedef __attribute__((ext_vector_type(8))) __bf16 bf16x8;
typedef __attribute__((ext_vector_type(4))) __bf16 bf16x4;
typedef __attribute__((ext_vector_type(4))) int i32x4;

#define NN 8192
#define FI 512
#define FO 256

#define MFMA16 __builtin_amdgcn_mfma_f32_16x16x32_bf16

// Direct global->LDS async copy, 16B per lane. LDS dst is wave-uniform base;
// HW writes lane i at base + i*16. Global src is per-lane. No VGPR dest =>
// the compiler cannot serialize these on register reuse (the R2/R4/R6 trap).
__device__ static inline void gld16(const bf16* g, bf16* l) {
  __builtin_amdgcn_global_load_lds(
      (const __attribute__((address_space(1))) unsigned int*)(g),
      (__attribute__((address_space(3))) unsigned int*)(l), 16, 0, 0);
}

// ---------------------------------------------------------------------------
// kw: W [512][256] f32 -> Wt_hi/Wt_lo [256][512] bf16 (transposed + split),
// so k1 can load B fragments straight from global (bf16x8 per lane).
// ---------------------------------------------------------------------------
__global__ __launch_bounds__(256) void kw_split(const float* __restrict__ W,
                                                bf16* __restrict__ wth,
                                                bf16* __restrict__ wtl) {
  const int idx = blockIdx.x * 256 + threadIdx.x;  // 512*256 = 131072
  const int k = idx >> 8, n = idx & 255;
  float x = W[idx];
  bf16 hi = (bf16)x;
  wth[(size_t)n * FI + k] = hi;
  wtl[(size_t)n * FI + k] = (bf16)(x - (float)hi);
}

// ---------------------------------------------------------------------------
// k1: Wh = h @ W + bW via split-bf16 MFMA (hi*hi + hi*lo + lo*hi, fp32 acc).
// Barrier-free main loop; wave = 16 rows x 64 cols (acc[4]). Short K (16
// steps) and L2-resident wth/wtl, so even serialized B loads cost only a few
// us across 2 blocks/CU. Epilogue stages whb through LDS -> one coalesced
// 8 KB linear store per block; f1/f2 via shfl-reduce + atomicAdd.
// Grid (256,2) = 512 blocks.
// ---------------------------------------------------------------------------
__global__ __launch_bounds__(256, 2) void k1_gemm(
    const float* __restrict__ h, const bf16* __restrict__ wth,
    const bf16* __restrict__ wtl, const float* __restrict__ bW,
    const float* __restrict__ a1, const float* __restrict__ a2,
    bf16* __restrict__ whb, float* __restrict__ f1, float* __restrict__ f2) {
  __shared__ bf16 stg[128 * 32];  // [n_local][il], 8 KB
  const int t = threadIdx.x;
  const int lane = t & 63, w = t >> 6;
  const int m16 = lane & 15, q = lane >> 4;
  const int wr = w & 1, wn = w >> 1;
  const int rb = blockIdx.x, bj = blockIdx.y;
  const int row = rb * 32 + wr * 16 + m16;  // A-fragment row for this lane
  const int nb = bj * 128 + wn * 64;

  const f32x4 z4 = {0.f, 0.f, 0.f, 0.f};
  f32x4 acc[4];
#pragma unroll
  for (int nn = 0; nn < 4; ++nn) acc[nn] = z4;

  const float* hrow = h + (size_t)row * FI + q * 8;
  const bf16* wthp = wth + (size_t)(nb + m16) * FI + q * 8;
  const bf16* wtlp = wtl + (size_t)(nb + m16) * FI + q * 8;

  f32x4 nh0 = *(const f32x4*)(hrow);
  f32x4 nh1 = *(const f32x4*)(hrow + 4);

  const int KT = FI / 32;
  for (int kt = 0; kt < KT; ++kt) {
    bf16x8 bh[4], bl[4];
#pragma unroll
    for (int nn = 0; nn < 4; ++nn) {
      const size_t woff = (size_t)(nn * 16) * FI + kt * 32;
      bh[nn] = *(const bf16x8*)(wthp + woff);
      bl[nn] = *(const bf16x8*)(wtlp + woff);
    }
    const f32x4 h0 = nh0, h1 = nh1;
    const int ktn = (kt + 1 < KT) ? kt + 1 : kt;
    nh0 = *(const f32x4*)(hrow + ktn * 32);
    nh1 = *(const f32x4*)(hrow + ktn * 32 + 4);
    bf16x8 hh, hl;
#pragma unroll
    for (int x = 0; x < 4; ++x) {
      float v = h0[x];
      bf16 hi = (bf16)v;
      hh[x] = hi;
      hl[x] = (bf16)(v - (float)hi);
      float v2 = h1[x];
      bf16 hi2 = (bf16)v2;
      hh[4 + x] = hi2;
      hl[4 + x] = (bf16)(v2 - (float)hi2);
    }
#pragma unroll
    for (int nn = 0; nn < 4; ++nn) {
      acc[nn] = MFMA16(hh, bh[nn], acc[nn], 0, 0, 0);
      acc[nn] = MFMA16(hl, bh[nn], acc[nn], 0, 0, 0);
      acc[nn] = MFMA16(hh, bl[nn], acc[nn], 0, 0, 0);
    }
  }
  // Epilogue. C/D layout: col = lane&15 (n), row = q*4+reg (i within 16-tile).
  float f1p[4] = {}, f2p[4] = {};
  const int il = wr * 16 + q * 4;
#pragma unroll
  for (int nn = 0; nn < 4; ++nn) {
    const int n = nb + nn * 16 + m16;
    const int nl = wn * 64 + nn * 16 + m16;  // local n within block (0..127)
    const float bw = bW[n], av1 = a1[n], av2 = a2[n];
    bf16x4 st;
#pragma unroll
    for (int reg = 0; reg < 4; ++reg) {
      float wh = acc[nn][reg] + bw;
      st[reg] = (bf16)wh;
      f1p[reg] += wh * av1;
      f2p[reg] += wh * av2;
    }
    *(bf16x4*)&stg[nl * 32 + il] = st;
  }
#pragma unroll
  for (int m = 1; m < 16; m <<= 1) {
#pragma unroll
    for (int reg = 0; reg < 4; ++reg) {
      f1p[reg] += __shfl_xor(f1p[reg], m);
      f2p[reg] += __shfl_xor(f2p[reg], m);
    }
  }
  if (m16 == 0) {
#pragma unroll
    for (int reg = 0; reg < 4; ++reg) {
      const int i = rb * 32 + wr * 16 + q * 4 + reg;
      atomicAdd(&f1[i], f1p[reg]);
      atomicAdd(&f2[i], f2p[reg]);
    }
  }
  __syncthreads();
  // Coalesced whb store: block region is 4096 contiguous bf16 (8 KB).
  bf16x8* dst = (bf16x8*)(whb + (size_t)rb * (FO * 32) + (size_t)bj * (128 * 32));
  const bf16x8* srcv = (const bf16x8*)stg;
#pragma unroll
  for (int u = 0; u < 2; ++u) dst[t * 2 + u] = srcv[t * 2 + u];
}

// ---------------------------------------------------------------------------
// k4a: masked exp-scores, pure streaming (no LDS, no barriers, no MFMA).
// Wave = 16 rows x 512 j; lane (m16,q) scores row m16, j = q*8..+7 per 32-j
// tile = exactly one MFMA A-fragment lane -> P tile written as 64 lanes x
// bf16x8 = 1 KB coalesced. One atomicAdd per row per wave into l (prezeroed).
// Softmax shift: sh = lrelu(ci + 8) >= row max (|f2| << 8); cancels exactly
// in num/denom. 8192 waves = 2048 blocks; adj 268 MB R + P 134 MB W.
// ---------------------------------------------------------------------------
__global__ __launch_bounds__(256) void k4a_scores(
    const int* __restrict__ adj, const float* __restrict__ f1,
    const float* __restrict__ f2, const float* __restrict__ ba_p,
    bf16* __restrict__ P, float* __restrict__ l) {
  const int t = threadIdx.x;
  const int lane = t & 63, w = t >> 6;
  const int m16 = lane & 15, q = lane >> 4;
  const int gw = blockIdx.x * 4 + w;  // 0..8191
  const int ib = gw >> 4;             // row-tile (16 rows), 0..511
  const int js = gw & 15;             // j-split (512 j), 0..15
  const int row = ib * 16 + m16;
  const int j0 = js * 512;

  const float ba = *ba_p;
  const float ci = f1[row] + ba;
  const float arg0 = ci + 8.0f;
  const float sh = fmaxf(arg0, 0.2f * arg0);

  const int* arow = adj + (size_t)row * NN + j0 + q * 8;
  const float* frow = f2 + j0 + q * 8;
  // P tile a = ib*256 + js*16 + jt; lane slot = tile*512 + lane*8
  bf16* ptile = P + (size_t)(ib * 256 + js * 16) * 512 + lane * 8;

  float lreg = 0.f;
#pragma unroll 4
  for (int jt = 0; jt < 16; ++jt) {
    i32x4 a0 = *(const i32x4*)(arow + jt * 32);
    i32x4 a1 = *(const i32x4*)(arow + jt * 32 + 4);
    f32x4 g0 = *(const f32x4*)(frow + jt * 32);
    f32x4 g1 = *(const f32x4*)(frow + jt * 32 + 4);
    float pv[8];
#pragma unroll
    for (int x = 0; x < 4; ++x) {
      float arg = ci + g0[x];
      float e = fmaxf(arg, 0.2f * arg);
      pv[x] = (a0[x] > 0) ? __expf(e - sh) : 0.f;
      float arg2 = ci + g1[x];
      float e2 = fmaxf(arg2, 0.2f * arg2);
      pv[4 + x] = (a1[x] > 0) ? __expf(e2 - sh) : 0.f;
    }
    bf16x8 pb;
#pragma unroll
    for (int x = 0; x < 8; ++x) {
      lreg += pv[x];
      pb[x] = (bf16)pv[x];
    }
    *(bf16x8*)(ptile + (size_t)jt * 512) = pb;
  }
  // sum over the 4 q-lanes sharing a row, then one atomic per row
  lreg += __shfl_xor(lreg, 16);
  lreg += __shfl_xor(lreg, 32);
  if (q == 0) atomicAdd(&l[row], lreg);
}

// ---------------------------------------------------------------------------
// k4b: out = (P @ Wh) / l.  M=8192, N=256, K=8192. m97-style double-buffered
// LDS GEMM with global_load_lds width-16 staging (the ONLY load path this
// compiler schedules well: R2/R3 sank reg loads to uses and serialized at
// 32-44 VGPR; R4's pin spilled 1 GB; R6's named dbuf dissolved to VGPR=32
// and 340 us). Both operands are fragment-major, so the stage is a LINEAR
// copy -- satisfies global_load_lds's lane-linear LDS destination rule --
// and ds_reads need zero layout work.
// Block = 32 rows x 128 cols, 256 threads (4 waves: wr = m-tile, wn =
// n-half); K-step 32. Per step: 10 x 1KB staged chunks (A 2, B 8), then per
// wave 5 x ds_read_b128 + 4 MFMA, ONE barrier. Grid (256,2) = 512 blocks =
// 2/CU so one block's vmcnt(0)+barrier drain hides under the other's
// compute. LDS 20 KB.  whb (4 MB) is L2-resident; P read 2x (bj halves),
// second pass largely L3-resident (134 MB < 256 MB).
// ---------------------------------------------------------------------------
__global__ __launch_bounds__(256, 2) void k4b_gemm(
    const bf16* __restrict__ P, const bf16* __restrict__ whb,
    const float* __restrict__ l, float* __restrict__ out) {
  __shared__ bf16 Ab[2][32 * 32];   // [buf][m-tile(2) x 512], 2 KB/buf
  __shared__ bf16 Bb[2][128 * 32];  // [buf][n_loc x 32], 8 KB/buf
  const int t = threadIdx.x;
  const int lane = t & 63, w = t >> 6;  // 4 waves
  const int m16 = lane & 15, q = lane >> 4;
  const int wr = w & 1, wn = w >> 1;    // wr: m-tile, wn: n-half (64 cols)
  const int rb = blockIdx.x, bj = blockIdx.y;
  const int i0 = rb * 32;

  // staging sources (per-lane global addresses, lane-linear)
  const bf16* asrc = P + ((size_t)(rb * 2 + w) * 256) * 512 + lane * 8;  // w<2
  const bf16* bsrc0 = whb + (size_t)bj * 4096 + (w * 2 + 0) * 512 + lane * 8;
  const bf16* bsrc1 = whb + (size_t)bj * 4096 + (w * 2 + 1) * 512 + lane * 8;

#define K4B_STAGE(buf, kt)                                                    \
  {                                                                           \
    if (w < 2) gld16(asrc + (size_t)(kt) * 512, &Ab[buf][w * 512]);           \
    gld16(bsrc0 + (size_t)(kt) * 8192, &Bb[buf][(w * 2 + 0) * 512]);          \
    gld16(bsrc1 + (size_t)(kt) * 8192, &Bb[buf][(w * 2 + 1) * 512]);          \
  }

  const f32x4 z4 = {0.f, 0.f, 0.f, 0.f};
  f32x4 acc0 = z4, acc1 = z4, acc2 = z4, acc3 = z4;

  K4B_STAGE(0, 0);
  __syncthreads();

  const int KB = NN / 32;  // 256
  int cur = 0;
  for (int kt = 0; kt < KB; ++kt) {
    const int ktn = (kt + 1 < KB) ? kt + 1 : kt;  // clamped (harmless reload)
    K4B_STAGE(cur ^ 1, ktn);
    // compute on buf cur: A frag = this wave's m-tile, lane-linear slot
    bf16x8 af = *(const bf16x8*)&Ab[cur][wr * 512 + lane * 8];
    const int bbase = (wn * 64 + m16) * 32 + q * 8;
    bf16x8 b0 = *(const bf16x8*)&Bb[cur][bbase];
    bf16x8 b1 = *(const bf16x8*)&Bb[cur][bbase + 16 * 32];
    bf16x8 b2 = *(const bf16x8*)&Bb[cur][bbase + 32 * 32];
    bf16x8 b3 = *(const bf16x8*)&Bb[cur][bbase + 48 * 32];
    acc0 = MFMA16(af, b0, acc0, 0, 0, 0);
    acc1 = MFMA16(af, b1, acc1, 0, 0, 0);
    acc2 = MFMA16(af, b2, acc2, 0, 0, 0);
    acc3 = MFMA16(af, b3, acc3, 0, 0, 0);
    __syncthreads();  // staged next buf ready; cur reads done before overwrite
    cur ^= 1;
  }
#undef K4B_STAGE

  // Epilogue: divide by l and store. C/D: col = lane&15 (n), row = q*4+reg.
  const int r0 = i0 + wr * 16 + q * 4;
  float rl[4];
#pragma unroll
  for (int reg = 0; reg < 4; ++reg) rl[reg] = 1.0f / l[r0 + reg];
  f32x4 accs[4] = {acc0, acc1, acc2, acc3};
#pragma unroll
  for (int nn = 0; nn < 4; ++nn) {
    const int n = bj * 128 + wn * 64 + nn * 16 + m16;
#pragma unroll
    for (int reg = 0; reg < 4; ++reg) {
      out[(size_t)(r0 + reg) * FO + n] = accs[nn][reg] * rl[reg];
    }
  }
}

// ---------------------------------------------------------------------------
// Workspace layout:
//   [0, 4MB)          whb  (bf16 Wh, fragment-major)
//   4MB               f1   (32 KB)
//   +32KB             f2   (32 KB)
//   +64KB             l    (32 KB)   <- f1/f2/l contiguous, one 96 KB memset
//   4MB+96KB          wth (256 KB), wtl (256 KB)
//   8MB               P    (bf16 scores, A-fragment-major, 134.2 MB)
// total ~143 MB
// ---------------------------------------------------------------------------
extern "C" void kernel_launch(void* const* d_in, const int* in_sizes, int n_in,
                              void* d_out, int out_size, void* d_ws, size_t ws_size,
                              hipStream_t stream) {
  const float* h   = (const float*)d_in[0];
  const int*   adj = (const int*)d_in[1];
  const float* W   = (const float*)d_in[2];
  const float* bW  = (const float*)d_in[3];
  const float* a1  = (const float*)d_in[4];
  const float* a2  = (const float*)d_in[5];
  const float* ba  = (const float*)d_in[6];
  float* out = (float*)d_out;

  char* ws = (char*)d_ws;
  bf16* whb = (bf16*)ws;
  float* f1 = (float*)(ws + 4u * 1024 * 1024);
  float* f2 = (float*)(ws + 4u * 1024 * 1024 + 32 * 1024);
  float* l  = (float*)(ws + 4u * 1024 * 1024 + 64 * 1024);
  bf16* wth = (bf16*)(ws + 4u * 1024 * 1024 + 96 * 1024);
  bf16* wtl = wth + (size_t)FO * FI;
  bf16* P   = (bf16*)(ws + 8u * 1024 * 1024);

  hipMemsetAsync(f1, 0, 96 * 1024, stream);  // zero f1+f2+l (atomic targets)

  kw_split<<<FI * FO / 256, 256, 0, stream>>>(W, wth, wtl);
  k1_gemm<<<dim3(NN / 32, 2), 256, 0, stream>>>(h, wth, wtl, bW, a1, a2, whb, f1, f2);
  k4a_scores<<<NN / 4, 256, 0, stream>>>(adj, f1, f2, ba, P, l);  // 2048 blocks
  k4b_gemm<<<dim3(NN / 32, 2), 256, 0, stream>>>(P, whb, l, out);
}